// Round 6
// baseline (201.156 us; speedup 1.0000x reference)
//
#include <hip/hip_runtime.h>
#include <math.h>

constexpr int cH = 56, cW = 56, cC = 96, cDI = 192, cN = 16, cDR = 6, cK = 4, cMH = 384;
constexpr int cL = cH * cW;          // 3136
constexpr int cNC = 98;              // scan chunks
constexpr int cCH = 32;              // chunk length
constexpr float LOG2E = 1.44269504088896340736f;

__device__ __forceinline__ float fast_exp2(float x) { return __builtin_amdgcn_exp2f(x); }
__device__ __forceinline__ float siluf(float x) { return x / (1.f + expf(-x)); }
__device__ __forceinline__ float geluf(float x) {
    float x3 = x * x * x;
    return 0.5f * x * (1.f + tanhf(0.7978845608028654f * (x + 0.044715f * x3)));
}

// ======== fused LayerNorm(96) + GEMM: C = LN(A) @ B [+bias][gelu] ========
// block 256, BM=64, BN=32, K=96 fixed
template <int ACT, bool HASB>
__global__ __launch_bounds__(256) void gemm_ln_tile(
    const float* __restrict__ A, const float* __restrict__ g, const float* __restrict__ b,
    const float* __restrict__ B, const float* __restrict__ bias,
    float* __restrict__ C, int M, int Nn) {
    __shared__ float As[64][100];
    __shared__ float Bs2[32][32];
    __shared__ float gB[96], bB[96], rowM[64], rowR[64];
    int tid = threadIdx.x;
    int row0 = blockIdx.y * 64;
    int n0 = blockIdx.x * 32;
    if (tid < 96) { gB[tid] = g[tid]; bB[tid] = b[tid]; }
#pragma unroll
    for (int t = 0; t < 6; t++) {
        int f = tid + t * 256;
        int ar = f / 24, ac4 = (f % 24) * 4;
        const float4 v = *reinterpret_cast<const float4*>(A + (size_t)(row0 + ar) * 96 + ac4);
        *reinterpret_cast<float4*>(&As[ar][ac4]) = v;
    }
    __syncthreads();
    {
        int row = tid >> 2, q = tid & 3;
        float s = 0.f, sq = 0.f;
#pragma unroll
        for (int c = 0; c < 24; c++) {
            float v = As[row][q * 24 + c];
            s += v; sq += v * v;
        }
        s += __shfl_xor(s, 1); sq += __shfl_xor(sq, 1);
        s += __shfl_xor(s, 2); sq += __shfl_xor(sq, 2);
        if (q == 0) {
            float m = s * (1.f / 96.f);
            float var = sq * (1.f / 96.f) - m * m;
            rowM[row] = m;
            rowR[row] = rsqrtf(var + 1e-5f);
        }
    }
    __syncthreads();
    for (int i = tid; i < 64 * 96; i += 256) {
        int r = i / 96, c = i % 96;
        As[r][c] = (As[r][c] - rowM[r]) * rowR[r] * gB[c] + bB[c];
    }
    __syncthreads();
    int tx = tid & 15, ty = tid >> 4;
    float acc[4][2] = {{0.f, 0.f}, {0.f, 0.f}, {0.f, 0.f}, {0.f, 0.f}};
#pragma unroll
    for (int kt = 0; kt < 3; kt++) {
        {
            int br = tid >> 3, bc = (tid & 7) * 4;
            const float4 v = *reinterpret_cast<const float4*>(
                B + (size_t)(kt * 32 + br) * Nn + n0 + bc);
            *reinterpret_cast<float4*>(&Bs2[br][bc]) = v;
        }
        __syncthreads();
#pragma unroll
        for (int k4 = 0; k4 < 8; k4++) {
            float4 a0 = *reinterpret_cast<float4*>(&As[ty * 4 + 0][kt * 32 + k4 * 4]);
            float4 a1 = *reinterpret_cast<float4*>(&As[ty * 4 + 1][kt * 32 + k4 * 4]);
            float4 a2 = *reinterpret_cast<float4*>(&As[ty * 4 + 2][kt * 32 + k4 * 4]);
            float4 a3 = *reinterpret_cast<float4*>(&As[ty * 4 + 3][kt * 32 + k4 * 4]);
            float2 b0 = *reinterpret_cast<float2*>(&Bs2[k4 * 4 + 0][tx * 2]);
            float2 b1 = *reinterpret_cast<float2*>(&Bs2[k4 * 4 + 1][tx * 2]);
            float2 b2 = *reinterpret_cast<float2*>(&Bs2[k4 * 4 + 2][tx * 2]);
            float2 b3 = *reinterpret_cast<float2*>(&Bs2[k4 * 4 + 3][tx * 2]);
            acc[0][0] = fmaf(a0.x, b0.x, acc[0][0]); acc[0][1] = fmaf(a0.x, b0.y, acc[0][1]);
            acc[1][0] = fmaf(a1.x, b0.x, acc[1][0]); acc[1][1] = fmaf(a1.x, b0.y, acc[1][1]);
            acc[2][0] = fmaf(a2.x, b0.x, acc[2][0]); acc[2][1] = fmaf(a2.x, b0.y, acc[2][1]);
            acc[3][0] = fmaf(a3.x, b0.x, acc[3][0]); acc[3][1] = fmaf(a3.x, b0.y, acc[3][1]);
            acc[0][0] = fmaf(a0.y, b1.x, acc[0][0]); acc[0][1] = fmaf(a0.y, b1.y, acc[0][1]);
            acc[1][0] = fmaf(a1.y, b1.x, acc[1][0]); acc[1][1] = fmaf(a1.y, b1.y, acc[1][1]);
            acc[2][0] = fmaf(a2.y, b1.x, acc[2][0]); acc[2][1] = fmaf(a2.y, b1.y, acc[2][1]);
            acc[3][0] = fmaf(a3.y, b1.x, acc[3][0]); acc[3][1] = fmaf(a3.y, b1.y, acc[3][1]);
            acc[0][0] = fmaf(a0.z, b2.x, acc[0][0]); acc[0][1] = fmaf(a0.z, b2.y, acc[0][1]);
            acc[1][0] = fmaf(a1.z, b2.x, acc[1][0]); acc[1][1] = fmaf(a1.z, b2.y, acc[1][1]);
            acc[2][0] = fmaf(a2.z, b2.x, acc[2][0]); acc[2][1] = fmaf(a2.z, b2.y, acc[2][1]);
            acc[3][0] = fmaf(a3.z, b2.x, acc[3][0]); acc[3][1] = fmaf(a3.z, b2.y, acc[3][1]);
            acc[0][0] = fmaf(a0.w, b3.x, acc[0][0]); acc[0][1] = fmaf(a0.w, b3.y, acc[0][1]);
            acc[1][0] = fmaf(a1.w, b3.x, acc[1][0]); acc[1][1] = fmaf(a1.w, b3.y, acc[1][1]);
            acc[2][0] = fmaf(a2.w, b3.x, acc[2][0]); acc[2][1] = fmaf(a2.w, b3.y, acc[2][1]);
            acc[3][0] = fmaf(a3.w, b3.x, acc[3][0]); acc[3][1] = fmaf(a3.w, b3.y, acc[3][1]);
        }
        __syncthreads();
    }
    int cc = n0 + tx * 2;
    float bx_ = 0.f, by_ = 0.f;
    if (HASB) { bx_ = bias[cc]; by_ = bias[cc + 1]; }
#pragma unroll
    for (int i = 0; i < 4; i++) {
        int rr = row0 + ty * 4 + i;
        float v0 = acc[i][0], v1 = acc[i][1];
        if (HASB) { v0 += bx_; v1 += by_; }
        if (ACT == 1) { v0 = geluf(v0); v1 = geluf(v1); }
        float2 o; o.x = v0; o.y = v1;
        *reinterpret_cast<float2*>(C + (size_t)rr * Nn + cc) = o;
    }
}

// ======== plain LDS-tiled fp32 GEMM (fc2) ========
template <int ACT, bool HASB, bool HASR>
__global__ __launch_bounds__(256) void gemm_tile_kernel(
    const float* __restrict__ A, const float* __restrict__ B,
    const float* __restrict__ bias, const float* __restrict__ res,
    float* __restrict__ C, int M, int Nn, int Kk) {
    __shared__ float As[64][36];
    __shared__ float Bs[32][32];
    int tid = threadIdx.x;
    int tx = tid & 15;
    int ty = tid >> 4;
    int row0 = blockIdx.y * 64;
    int n0 = blockIdx.x * 32;
    float acc[4][2] = {{0.f, 0.f}, {0.f, 0.f}, {0.f, 0.f}, {0.f, 0.f}};
    int nt = Kk >> 5;
    for (int kt = 0; kt < nt; kt++) {
#pragma unroll
        for (int t = 0; t < 2; t++) {
            int f = tid + t * 256;
            int ar = f >> 3, ac = (f & 7) * 4;
            const float4 v = *reinterpret_cast<const float4*>(
                A + (size_t)(row0 + ar) * Kk + kt * 32 + ac);
            *reinterpret_cast<float4*>(&As[ar][ac]) = v;
        }
        {
            int br = tid >> 3, bc = (tid & 7) * 4;
            const float4 v = *reinterpret_cast<const float4*>(
                B + (size_t)(kt * 32 + br) * Nn + n0 + bc);
            *reinterpret_cast<float4*>(&Bs[br][bc]) = v;
        }
        __syncthreads();
#pragma unroll
        for (int k4 = 0; k4 < 8; k4++) {
            float4 a0 = *reinterpret_cast<float4*>(&As[ty * 4 + 0][k4 * 4]);
            float4 a1 = *reinterpret_cast<float4*>(&As[ty * 4 + 1][k4 * 4]);
            float4 a2 = *reinterpret_cast<float4*>(&As[ty * 4 + 2][k4 * 4]);
            float4 a3 = *reinterpret_cast<float4*>(&As[ty * 4 + 3][k4 * 4]);
            float2 b0 = *reinterpret_cast<float2*>(&Bs[k4 * 4 + 0][tx * 2]);
            float2 b1 = *reinterpret_cast<float2*>(&Bs[k4 * 4 + 1][tx * 2]);
            float2 b2 = *reinterpret_cast<float2*>(&Bs[k4 * 4 + 2][tx * 2]);
            float2 b3 = *reinterpret_cast<float2*>(&Bs[k4 * 4 + 3][tx * 2]);
            acc[0][0] = fmaf(a0.x, b0.x, acc[0][0]); acc[0][1] = fmaf(a0.x, b0.y, acc[0][1]);
            acc[1][0] = fmaf(a1.x, b0.x, acc[1][0]); acc[1][1] = fmaf(a1.x, b0.y, acc[1][1]);
            acc[2][0] = fmaf(a2.x, b0.x, acc[2][0]); acc[2][1] = fmaf(a2.x, b0.y, acc[2][1]);
            acc[3][0] = fmaf(a3.x, b0.x, acc[3][0]); acc[3][1] = fmaf(a3.x, b0.y, acc[3][1]);
            acc[0][0] = fmaf(a0.y, b1.x, acc[0][0]); acc[0][1] = fmaf(a0.y, b1.y, acc[0][1]);
            acc[1][0] = fmaf(a1.y, b1.x, acc[1][0]); acc[1][1] = fmaf(a1.y, b1.y, acc[1][1]);
            acc[2][0] = fmaf(a2.y, b1.x, acc[2][0]); acc[2][1] = fmaf(a2.y, b1.y, acc[2][1]);
            acc[3][0] = fmaf(a3.y, b1.x, acc[3][0]); acc[3][1] = fmaf(a3.y, b1.y, acc[3][1]);
            acc[0][0] = fmaf(a0.z, b2.x, acc[0][0]); acc[0][1] = fmaf(a0.z, b2.y, acc[0][1]);
            acc[1][0] = fmaf(a1.z, b2.x, acc[1][0]); acc[1][1] = fmaf(a1.z, b2.y, acc[1][1]);
            acc[2][0] = fmaf(a2.z, b2.x, acc[2][0]); acc[2][1] = fmaf(a2.z, b2.y, acc[2][1]);
            acc[3][0] = fmaf(a3.z, b2.x, acc[3][0]); acc[3][1] = fmaf(a3.z, b2.y, acc[3][1]);
            acc[0][0] = fmaf(a0.w, b3.x, acc[0][0]); acc[0][1] = fmaf(a0.w, b3.y, acc[0][1]);
            acc[1][0] = fmaf(a1.w, b3.x, acc[1][0]); acc[1][1] = fmaf(a1.w, b3.y, acc[1][1]);
            acc[2][0] = fmaf(a2.w, b3.x, acc[2][0]); acc[2][1] = fmaf(a2.w, b3.y, acc[2][1]);
            acc[3][0] = fmaf(a3.w, b3.x, acc[3][0]); acc[3][1] = fmaf(a3.w, b3.y, acc[3][1]);
        }
        __syncthreads();
    }
    int cc = n0 + tx * 2;
    float bx_ = 0.f, by_ = 0.f;
    if (HASB) { bx_ = bias[cc]; by_ = bias[cc + 1]; }
#pragma unroll
    for (int i = 0; i < 4; i++) {
        int rr = row0 + ty * 4 + i;
        float v0 = acc[i][0], v1 = acc[i][1];
        if (HASB) { v0 += bx_; v1 += by_; }
        if (ACT == 1) { v0 = geluf(v0); v1 = geluf(v1); }
        if (HASR) {
            const float2 r2 = *reinterpret_cast<const float2*>(res + (size_t)rr * Nn + cc);
            v0 += r2.x; v1 += r2.y;
        }
        float2 o; o.x = v0; o.y = v1;
        *reinterpret_cast<float2*>(C + (size_t)rr * Nn + cc) = o;
    }
}

// ======== fused combine + out-LN + silu(z) + out_proj GEMM + residual ========
// block 256, BM=16 rows, BN=96 (full), K=192
__global__ __launch_bounds__(256) void lnout_gemm_kernel(
    const float* __restrict__ ysS, const float* __restrict__ xz,
    const float* __restrict__ g, const float* __restrict__ b,
    const float* __restrict__ W, const float* __restrict__ resx,
    float* __restrict__ C) {
    __shared__ float As[16][196];
    __shared__ float Bs[32][96];
    __shared__ float gB[192], bB[192], rowM[16], rowR[16];
    int tid = threadIdx.x;
    int row0 = blockIdx.x * 16;
    if (tid < 192) { gB[tid] = g[tid]; bB[tid] = b[tid]; }
    // phase 1: gather 4-direction sum
#pragma unroll
    for (int t = 0; t < 3; t++) {
        int f = tid + t * 256;
        int rr = f / 48, d4 = (f % 48) * 4;
        int l = row0 + rr;
        int h_ = l / cW, w_ = l % cW;
        int lc = w_ * cH + h_;
        const float4 y0 = *reinterpret_cast<const float4*>(ysS + (size_t)(0 * cL + l) * cDI + d4);
        const float4 y1 = *reinterpret_cast<const float4*>(ysS + (size_t)(1 * cL + lc) * cDI + d4);
        const float4 y2 = *reinterpret_cast<const float4*>(ysS + (size_t)(2 * cL + (cL - 1 - l)) * cDI + d4);
        const float4 y3 = *reinterpret_cast<const float4*>(ysS + (size_t)(3 * cL + (cL - 1 - lc)) * cDI + d4);
        float4 o;
        o.x = y0.x + y1.x + y2.x + y3.x;
        o.y = y0.y + y1.y + y2.y + y3.y;
        o.z = y0.z + y1.z + y2.z + y3.z;
        o.w = y0.w + y1.w + y2.w + y3.w;
        *reinterpret_cast<float4*>(&As[rr][d4]) = o;
    }
    __syncthreads();
    // stats: 16 threads per row
    {
        int row = tid >> 4, seg = tid & 15;
        float s = 0.f, sq = 0.f;
#pragma unroll
        for (int c = 0; c < 12; c++) {
            float v = As[row][seg * 12 + c];
            s += v; sq += v * v;
        }
        s += __shfl_xor(s, 1); sq += __shfl_xor(sq, 1);
        s += __shfl_xor(s, 2); sq += __shfl_xor(sq, 2);
        s += __shfl_xor(s, 4); sq += __shfl_xor(sq, 4);
        s += __shfl_xor(s, 8); sq += __shfl_xor(sq, 8);
        if (seg == 0) {
            float m = s * (1.f / 192.f);
            float var = sq * (1.f / 192.f) - m * m;
            rowM[row] = m;
            rowR[row] = rsqrtf(var + 1e-5f);
        }
    }
    __syncthreads();
    // normalize * silu(z)
    for (int i = tid; i < 16 * 192; i += 256) {
        int rr = i / 192, c = i % 192;
        int l = row0 + rr;
        float z = xz[(size_t)l * (2 * cDI) + cDI + c];
        As[rr][c] = ((As[rr][c] - rowM[rr]) * rowR[rr] * gB[c] + bB[c]) * siluf(z);
    }
    __syncthreads();
    // GEMM: rows = ty + 8*i (i<2), cols = tx*3..+2
    int tx = tid & 31, ty = tid >> 5;
    int c0 = tx * 3;
    float acc[2][3] = {{0.f, 0.f, 0.f}, {0.f, 0.f, 0.f}};
#pragma unroll
    for (int kt = 0; kt < 6; kt++) {
        for (int i2 = tid; i2 < 32 * 96; i2 += 256) {
            int kk = i2 / 96, c = i2 % 96;
            Bs[kk][c] = W[(size_t)(kt * 32 + kk) * 96 + c];
        }
        __syncthreads();
#pragma unroll
        for (int k = 0; k < 32; k++) {
            float a0 = As[ty][kt * 32 + k];
            float a1 = As[ty + 8][kt * 32 + k];
            float b0 = Bs[k][c0], b1 = Bs[k][c0 + 1], b2 = Bs[k][c0 + 2];
            acc[0][0] = fmaf(a0, b0, acc[0][0]);
            acc[0][1] = fmaf(a0, b1, acc[0][1]);
            acc[0][2] = fmaf(a0, b2, acc[0][2]);
            acc[1][0] = fmaf(a1, b0, acc[1][0]);
            acc[1][1] = fmaf(a1, b1, acc[1][1]);
            acc[1][2] = fmaf(a1, b2, acc[1][2]);
        }
        __syncthreads();
    }
#pragma unroll
    for (int i = 0; i < 2; i++) {
        int rr = row0 + ty + 8 * i;
#pragma unroll
        for (int j = 0; j < 3; j++)
            C[(size_t)rr * 96 + c0 + j] = acc[i][j] + resx[(size_t)rr * 96 + c0 + j];
    }
}

// ---------------- depthwise 3x3 conv + bias + silu ----------------
__global__ void conv_silu_kernel(const float* __restrict__ xz, const float* __restrict__ cw,
                                 const float* __restrict__ cb, float* __restrict__ out) {
    int idx = blockIdx.x * 256 + threadIdx.x;
    if (idx >= cL * cDI) return;
    int d = idx % cDI;
    int l = idx / cDI;
    int h = l / cW, w = l % cW;
    float s = cb[d];
#pragma unroll
    for (int dh = 0; dh < 3; dh++) {
        int hh = h + dh - 1;
        if (hh < 0 || hh >= cH) continue;
#pragma unroll
        for (int dw = 0; dw < 3; dw++) {
            int w2 = w + dw - 1;
            if (w2 < 0 || w2 >= cW) continue;
            s = fmaf(xz[(size_t)(hh * cW + w2) * (2 * cDI) + d], cw[(dh * 3 + dw) * cDI + d], s);
        }
    }
    out[idx] = siluf(s);
}

// ---------------- x_proj + dt_proj; dt in [k][j][d], Bs/Cs in [k][j][n] ----------------
__global__ void proj_kernel(const float* __restrict__ xconv, const float* __restrict__ xpw,
                            const float* __restrict__ dtw, const float* __restrict__ dtb,
                            float* __restrict__ dtT, float* __restrict__ Bsout,
                            float* __restrict__ Csout) {
    __shared__ float XS[16 * 193];
    __shared__ float DTS[6 * 16];
    __shared__ float DTW[cDI * cDR];
    int k = blockIdx.y;
    int p0 = blockIdx.x * 16;
    int tid = threadIdx.x;
    for (int i = tid; i < cDI * cDR; i += 256) DTW[i] = dtw[k * cDI * cDR + i];
    for (int idx = tid; idx < 16 * cDI; idx += 256) {
        int p = idx / cDI, d = idx % cDI;
        int j = p0 + p;
        int jj = (k >= 2) ? (cL - 1 - j) : j;
        int rrow = (k & 1) ? ((jj % cH) * cW + (jj / cH)) : jj;
        XS[p * 193 + d] = xconv[(size_t)rrow * cDI + d];
    }
    __syncthreads();
    for (int o = tid; o < 38 * 16; o += 256) {
        int c = o >> 4, p = o & 15;
        const float* wr = xpw + (size_t)(k * 38 + c) * cDI;
        const float* xr = XS + p * 193;
        float s = 0.f;
#pragma unroll 4
        for (int d = 0; d < cDI; d++) s = fmaf(wr[d], xr[d], s);
        if (c < 6) DTS[c * 16 + p] = s;
        else if (c < 22) Bsout[(size_t)(k * cL + p0 + p) * cN + (c - 6)] = s;
        else Csout[(size_t)(k * cL + p0 + p) * cN + (c - 22)] = s;
    }
    __syncthreads();
    for (int o = tid; o < cDI * 16; o += 256) {
        int d = o % cDI, p = o / cDI;
        float s = dtb[k * cDI + d];
#pragma unroll
        for (int r = 0; r < cDR; r++) s = fmaf(DTW[d * cDR + r], DTS[r * 16 + p], s);
        float sp = (s > 20.f) ? s : log1pf(expf(s));
        dtT[(size_t)(k * cL + p0 + p) * cDI + d] = sp;
    }
}

// physical-row walker (wave-uniform)
__device__ __forceinline__ void walker_init(int k, int j0, int& r, int& dr) {
    if (k == 0) { r = j0; dr = 1; }
    else if (k == 1) { r = (j0 % cH) * cW + (j0 / cH); dr = cW; }
    else if (k == 2) { r = cL - 1 - j0; dr = -1; }
    else { int jp = cL - 1 - j0; r = (jp % cH) * cW + (jp / cH); dr = -cW; }
}
__device__ __forceinline__ void walker_step(int& r, int dr) {
    r += dr;
    if (r >= cL) r -= cL - 1;
    else if (r < 0) r += cL - 1;
}

// ---------------- scan pass 1 ----------------
__global__ __launch_bounds__(192) void scan1_kernel(
    const float* __restrict__ dtT, const float* __restrict__ Bs,
    const float* __restrict__ xconv, const float* __restrict__ Alogs,
    float* __restrict__ carryP, float* __restrict__ carryH) {
    int c = blockIdx.x % cNC;
    int k = blockIdx.x / cNC;
    int d = threadIdx.x;
    int kd = k * cDI + d;
    int j0 = c * cCH;
    __shared__ float BS[cCH * cN];
    for (int i = threadIdx.x; i < cCH * cN; i += 192)
        BS[i] = Bs[(size_t)(k * cL + j0) * cN + i];
    float An2[cN];
#pragma unroll
    for (int n = 0; n < cN; n++)
        An2[n] = -fast_exp2(Alogs[kd * cN + n] * LOG2E) * LOG2E;
    int r, dr;
    walker_init(k, j0, r, dr);
    __syncthreads();
    float h[cN];
#pragma unroll
    for (int n = 0; n < cN; n++) h[n] = 0.f;
    float S = 0.f;
    const float* dtp = dtT + (size_t)(k * cL + j0) * cDI + d;
    for (int i = 0; i < cCH; i++) {
        float dt = dtp[(size_t)i * cDI];
        float xv = xconv[r * cDI + d];
        walker_step(r, dr);
        float dtx = dt * xv;
        S += dt;
        const float4 b0 = *reinterpret_cast<const float4*>(&BS[i * cN + 0]);
        const float4 b1 = *reinterpret_cast<const float4*>(&BS[i * cN + 4]);
        const float4 b2 = *reinterpret_cast<const float4*>(&BS[i * cN + 8]);
        const float4 b3 = *reinterpret_cast<const float4*>(&BS[i * cN + 12]);
        float bb[cN] = {b0.x, b0.y, b0.z, b0.w, b1.x, b1.y, b1.z, b1.w,
                        b2.x, b2.y, b2.z, b2.w, b3.x, b3.y, b3.z, b3.w};
#pragma unroll
        for (int n = 0; n < cN; n++) {
            float a = fast_exp2(An2[n] * dt);
            h[n] = fmaf(a, h[n], bb[n] * dtx);
        }
    }
    size_t cb = (size_t)(kd * cNC + c) * cN;
#pragma unroll
    for (int n = 0; n < cN; n++) {
        carryH[cb + n] = h[n];
        carryP[cb + n] = fast_exp2(An2[n] * S);
    }
}

// ---------------- scan pass 2 ----------------
__global__ void scan2_kernel(const float* __restrict__ carryP, const float* __restrict__ carryH,
                             float* __restrict__ hin) {
    int gid = blockIdx.x * 256 + threadIdx.x;
    if (gid >= cK * cDI * cN) return;
    int kd = gid / cN, n = gid % cN;
    float h = 0.f;
    for (int c = 0; c < cNC; c++) {
        size_t idxc = (size_t)(kd * cNC + c) * cN + n;
        hin[idxc] = h;
        h = fmaf(carryP[idxc], h, carryH[idxc]);
    }
}

// ---------------- scan pass 3 ----------------
__global__ __launch_bounds__(192) void scan3_kernel(
    const float* __restrict__ dtT, const float* __restrict__ Bs,
    const float* __restrict__ Cs, const float* __restrict__ xconv,
    const float* __restrict__ Alogs, const float* __restrict__ Ds,
    const float* __restrict__ hin, float* __restrict__ ysS) {
    int c = blockIdx.x % cNC;
    int k = blockIdx.x / cNC;
    int d = threadIdx.x;
    int kd = k * cDI + d;
    int j0 = c * cCH;
    __shared__ float BS[cCH * cN];
    __shared__ float CS[cCH * cN];
    for (int i = threadIdx.x; i < cCH * cN; i += 192) {
        BS[i] = Bs[(size_t)(k * cL + j0) * cN + i];
        CS[i] = Cs[(size_t)(k * cL + j0) * cN + i];
    }
    float An2[cN];
#pragma unroll
    for (int n = 0; n < cN; n++)
        An2[n] = -fast_exp2(Alogs[kd * cN + n] * LOG2E) * LOG2E;
    float Dv = Ds[kd];
    int r, dr;
    walker_init(k, j0, r, dr);
    float h[cN];
    size_t cb = (size_t)(kd * cNC + c) * cN;
#pragma unroll
    for (int n = 0; n < cN; n++) h[n] = hin[cb + n];
    __syncthreads();
    const float* dtp = dtT + (size_t)(k * cL + j0) * cDI + d;
    float* yp = ysS + (size_t)(k * cL + j0) * cDI + d;
    for (int i = 0; i < cCH; i++) {
        float dt = dtp[(size_t)i * cDI];
        float xv = xconv[r * cDI + d];
        walker_step(r, dr);
        float dtx = dt * xv;
        const float4 b0 = *reinterpret_cast<const float4*>(&BS[i * cN + 0]);
        const float4 b1 = *reinterpret_cast<const float4*>(&BS[i * cN + 4]);
        const float4 b2 = *reinterpret_cast<const float4*>(&BS[i * cN + 8]);
        const float4 b3 = *reinterpret_cast<const float4*>(&BS[i * cN + 12]);
        float bb[cN] = {b0.x, b0.y, b0.z, b0.w, b1.x, b1.y, b1.z, b1.w,
                        b2.x, b2.y, b2.z, b2.w, b3.x, b3.y, b3.z, b3.w};
        const float4 c0 = *reinterpret_cast<const float4*>(&CS[i * cN + 0]);
        const float4 c1 = *reinterpret_cast<const float4*>(&CS[i * cN + 4]);
        const float4 c2 = *reinterpret_cast<const float4*>(&CS[i * cN + 8]);
        const float4 c3 = *reinterpret_cast<const float4*>(&CS[i * cN + 12]);
        float cc[cN] = {c0.x, c0.y, c0.z, c0.w, c1.x, c1.y, c1.z, c1.w,
                        c2.x, c2.y, c2.z, c2.w, c3.x, c3.y, c3.z, c3.w};
        float y0 = 0.f, y1 = 0.f, y2 = 0.f, y3 = 0.f;
#pragma unroll
        for (int n = 0; n < cN; n += 4) {
            float a0 = fast_exp2(An2[n + 0] * dt);
            float a1 = fast_exp2(An2[n + 1] * dt);
            float a2 = fast_exp2(An2[n + 2] * dt);
            float a3 = fast_exp2(An2[n + 3] * dt);
            h[n + 0] = fmaf(a0, h[n + 0], bb[n + 0] * dtx);
            h[n + 1] = fmaf(a1, h[n + 1], bb[n + 1] * dtx);
            h[n + 2] = fmaf(a2, h[n + 2], bb[n + 2] * dtx);
            h[n + 3] = fmaf(a3, h[n + 3], bb[n + 3] * dtx);
            y0 = fmaf(h[n + 0], cc[n + 0], y0);
            y1 = fmaf(h[n + 1], cc[n + 1], y1);
            y2 = fmaf(h[n + 2], cc[n + 2], y2);
            y3 = fmaf(h[n + 3], cc[n + 3], y3);
        }
        yp[(size_t)i * cDI] = (y0 + y1) + (y2 + y3) + Dv * xv;
    }
}

extern "C" void kernel_launch(void* const* d_in, const int* in_sizes, int n_in,
                              void* d_out, int out_size, void* d_ws, size_t ws_size,
                              hipStream_t stream) {
    const float* x         = (const float*)d_in[0];
    const float* norm_g    = (const float*)d_in[1];
    const float* norm_b    = (const float*)d_in[2];
    const float* in_proj_w = (const float*)d_in[3];
    const float* conv_w    = (const float*)d_in[4];
    const float* conv_b    = (const float*)d_in[5];
    const float* x_proj_w  = (const float*)d_in[6];
    const float* dt_projs_w= (const float*)d_in[7];
    const float* dt_projs_b= (const float*)d_in[8];
    const float* A_logs    = (const float*)d_in[9];
    const float* Ds        = (const float*)d_in[10];
    const float* out_norm_g= (const float*)d_in[11];
    const float* out_norm_b= (const float*)d_in[12];
    const float* out_proj_w= (const float*)d_in[13];
    const float* norm2_g   = (const float*)d_in[14];
    const float* norm2_b   = (const float*)d_in[15];
    const float* fc1_w     = (const float*)d_in[16];
    const float* fc1_b     = (const float*)d_in[17];
    const float* fc2_w     = (const float*)d_in[18];
    const float* fc2_b     = (const float*)d_in[19];

    float* ws = (float*)d_ws;
    float* xz     = ws;                    // 1204224
    float* xconv  = ws + 1204224;          // 602112
    float* dtT    = ws + 1806336;          // 2408448  [k][j][d]
    float* Bs     = ws + 4214784;          // 200704   [k][j][n]
    float* Cs     = ws + 4415488;          // 200704   [k][j][n]
    float* hin    = ws + 4616192;          // K*DI*98*16 = 1204224
    float* cP     = ws + 5820416;          // 1204224
    float* cHh    = ws + 7024640;          // 1204224
    float* ysS    = ws + 8228864;          // 2408448  [k][j][d]
    float* x1     = ws + 10637312;         // 301056
    float* hm     = xz;                    // reuse xz after lnout_gemm
    float* out    = (float*)d_out;

    // 1. LN1 + in_proj (L,96)@(96,384)
    gemm_ln_tile<0, false><<<dim3(384 / 32, cL / 64), 256, 0, stream>>>(
        x, norm_g, norm_b, in_proj_w, nullptr, xz, cL, 2 * cDI);
    // 2. depthwise conv + silu
    conv_silu_kernel<<<(cL * cDI) / 256, 256, 0, stream>>>(xz, conv_w, conv_b, xconv);
    // 3. x_proj + dt_proj (scan-order outputs)
    proj_kernel<<<dim3(cL / 16, cK), 256, 0, stream>>>(xconv, x_proj_w, dt_projs_w,
                                                       dt_projs_b, dtT, Bs, Cs);
    // 4-6. chunked scan
    scan1_kernel<<<cK * cNC, 192, 0, stream>>>(dtT, Bs, xconv, A_logs, cP, cHh);
    scan2_kernel<<<(cK * cDI * cN + 255) / 256, 256, 0, stream>>>(cP, cHh, hin);
    scan3_kernel<<<cK * cNC, 192, 0, stream>>>(dtT, Bs, Cs, xconv, A_logs, Ds, hin, ysS);
    // 7. combine + out-LN + silu(z) + out_proj + residual(x)
    lnout_gemm_kernel<<<cL / 16, 256, 0, stream>>>(ysS, xz, out_norm_g, out_norm_b,
                                                   out_proj_w, x, x1);
    // 8. LN2 + fc1 + bias + gelu
    gemm_ln_tile<1, true><<<dim3(384 / 32, cL / 64), 256, 0, stream>>>(
        x1, norm2_g, norm2_b, fc1_w, fc1_b, hm, cL, cMH);
    // 9. fc2 + bias + residual(x1)
    gemm_tile_kernel<0, true, true><<<dim3(96 / 32, cL / 64), 256, 0, stream>>>(
        hm, fc2_w, fc2_b, x1, out, cL, cC, cMH);
}

// Round 7
// 160.939 us; speedup vs baseline: 1.2499x; 1.2499x over previous
//
#include <hip/hip_runtime.h>
#include <math.h>

constexpr int cH = 56, cW = 56, cC = 96, cDI = 192, cN = 16, cDR = 6, cK = 4, cMH = 384;
constexpr int cL = cH * cW;          // 3136
constexpr int cNC = 98;              // scan chunks
constexpr int cCH = 32;              // chunk length
constexpr float LOG2E = 1.44269504088896340736f;

__device__ __forceinline__ float fast_exp2(float x) { return __builtin_amdgcn_exp2f(x); }
__device__ __forceinline__ float siluf(float x) { return x / (1.f + expf(-x)); }
__device__ __forceinline__ float geluf(float x) {
    float x3 = x * x * x;
    return 0.5f * x * (1.f + tanhf(0.7978845608028654f * (x + 0.044715f * x3)));
}

// ======== fused LayerNorm(96) + GEMM: C = LN(A) @ B [+bias][gelu] ========
template <int ACT, bool HASB>
__global__ __launch_bounds__(256) void gemm_ln_tile(
    const float* __restrict__ A, const float* __restrict__ g, const float* __restrict__ b,
    const float* __restrict__ B, const float* __restrict__ bias,
    float* __restrict__ C, int M, int Nn) {
    __shared__ float As[64][100];
    __shared__ float Bs2[32][32];
    __shared__ float gB[96], bB[96], rowM[64], rowR[64];
    int tid = threadIdx.x;
    int row0 = blockIdx.y * 64;
    int n0 = blockIdx.x * 32;
    if (tid < 96) { gB[tid] = g[tid]; bB[tid] = b[tid]; }
#pragma unroll
    for (int t = 0; t < 6; t++) {
        int f = tid + t * 256;
        int ar = f / 24, ac4 = (f % 24) * 4;
        const float4 v = *reinterpret_cast<const float4*>(A + (size_t)(row0 + ar) * 96 + ac4);
        *reinterpret_cast<float4*>(&As[ar][ac4]) = v;
    }
    __syncthreads();
    {
        int row = tid >> 2, q = tid & 3;
        float s = 0.f, sq = 0.f;
#pragma unroll
        for (int c = 0; c < 24; c++) {
            float v = As[row][q * 24 + c];
            s += v; sq += v * v;
        }
        s += __shfl_xor(s, 1); sq += __shfl_xor(sq, 1);
        s += __shfl_xor(s, 2); sq += __shfl_xor(sq, 2);
        if (q == 0) {
            float m = s * (1.f / 96.f);
            float var = sq * (1.f / 96.f) - m * m;
            rowM[row] = m;
            rowR[row] = rsqrtf(var + 1e-5f);
        }
    }
    __syncthreads();
    for (int i = tid; i < 64 * 96; i += 256) {
        int r = i / 96, c = i % 96;
        As[r][c] = (As[r][c] - rowM[r]) * rowR[r] * gB[c] + bB[c];
    }
    __syncthreads();
    int tx = tid & 15, ty = tid >> 4;
    float acc[4][2] = {{0.f, 0.f}, {0.f, 0.f}, {0.f, 0.f}, {0.f, 0.f}};
#pragma unroll
    for (int kt = 0; kt < 3; kt++) {
        {
            int br = tid >> 3, bc = (tid & 7) * 4;
            const float4 v = *reinterpret_cast<const float4*>(
                B + (size_t)(kt * 32 + br) * Nn + n0 + bc);
            *reinterpret_cast<float4*>(&Bs2[br][bc]) = v;
        }
        __syncthreads();
#pragma unroll
        for (int k4 = 0; k4 < 8; k4++) {
            float4 a0 = *reinterpret_cast<float4*>(&As[ty * 4 + 0][kt * 32 + k4 * 4]);
            float4 a1 = *reinterpret_cast<float4*>(&As[ty * 4 + 1][kt * 32 + k4 * 4]);
            float4 a2 = *reinterpret_cast<float4*>(&As[ty * 4 + 2][kt * 32 + k4 * 4]);
            float4 a3 = *reinterpret_cast<float4*>(&As[ty * 4 + 3][kt * 32 + k4 * 4]);
            float2 b0 = *reinterpret_cast<float2*>(&Bs2[k4 * 4 + 0][tx * 2]);
            float2 b1 = *reinterpret_cast<float2*>(&Bs2[k4 * 4 + 1][tx * 2]);
            float2 b2 = *reinterpret_cast<float2*>(&Bs2[k4 * 4 + 2][tx * 2]);
            float2 b3 = *reinterpret_cast<float2*>(&Bs2[k4 * 4 + 3][tx * 2]);
            acc[0][0] = fmaf(a0.x, b0.x, acc[0][0]); acc[0][1] = fmaf(a0.x, b0.y, acc[0][1]);
            acc[1][0] = fmaf(a1.x, b0.x, acc[1][0]); acc[1][1] = fmaf(a1.x, b0.y, acc[1][1]);
            acc[2][0] = fmaf(a2.x, b0.x, acc[2][0]); acc[2][1] = fmaf(a2.x, b0.y, acc[2][1]);
            acc[3][0] = fmaf(a3.x, b0.x, acc[3][0]); acc[3][1] = fmaf(a3.x, b0.y, acc[3][1]);
            acc[0][0] = fmaf(a0.y, b1.x, acc[0][0]); acc[0][1] = fmaf(a0.y, b1.y, acc[0][1]);
            acc[1][0] = fmaf(a1.y, b1.x, acc[1][0]); acc[1][1] = fmaf(a1.y, b1.y, acc[1][1]);
            acc[2][0] = fmaf(a2.y, b1.x, acc[2][0]); acc[2][1] = fmaf(a2.y, b1.y, acc[2][1]);
            acc[3][0] = fmaf(a3.y, b1.x, acc[3][0]); acc[3][1] = fmaf(a3.y, b1.y, acc[3][1]);
            acc[0][0] = fmaf(a0.z, b2.x, acc[0][0]); acc[0][1] = fmaf(a0.z, b2.y, acc[0][1]);
            acc[1][0] = fmaf(a1.z, b2.x, acc[1][0]); acc[1][1] = fmaf(a1.z, b2.y, acc[1][1]);
            acc[2][0] = fmaf(a2.z, b2.x, acc[2][0]); acc[2][1] = fmaf(a2.z, b2.y, acc[2][1]);
            acc[3][0] = fmaf(a3.z, b2.x, acc[3][0]); acc[3][1] = fmaf(a3.z, b2.y, acc[3][1]);
            acc[0][0] = fmaf(a0.w, b3.x, acc[0][0]); acc[0][1] = fmaf(a0.w, b3.y, acc[0][1]);
            acc[1][0] = fmaf(a1.w, b3.x, acc[1][0]); acc[1][1] = fmaf(a1.w, b3.y, acc[1][1]);
            acc[2][0] = fmaf(a2.w, b3.x, acc[2][0]); acc[2][1] = fmaf(a2.w, b3.y, acc[2][1]);
            acc[3][0] = fmaf(a3.w, b3.x, acc[3][0]); acc[3][1] = fmaf(a3.w, b3.y, acc[3][1]);
        }
        __syncthreads();
    }
    int cc = n0 + tx * 2;
    float bx_ = 0.f, by_ = 0.f;
    if (HASB) { bx_ = bias[cc]; by_ = bias[cc + 1]; }
#pragma unroll
    for (int i = 0; i < 4; i++) {
        int rr = row0 + ty * 4 + i;
        float v0 = acc[i][0], v1 = acc[i][1];
        if (HASB) { v0 += bx_; v1 += by_; }
        if (ACT == 1) { v0 = geluf(v0); v1 = geluf(v1); }
        float2 o; o.x = v0; o.y = v1;
        *reinterpret_cast<float2*>(C + (size_t)rr * Nn + cc) = o;
    }
}

// ======== plain LDS-tiled fp32 GEMM ========
template <int ACT, bool HASB, bool HASR>
__global__ __launch_bounds__(256) void gemm_tile_kernel(
    const float* __restrict__ A, const float* __restrict__ B,
    const float* __restrict__ bias, const float* __restrict__ res,
    float* __restrict__ C, int M, int Nn, int Kk) {
    __shared__ float As[64][36];
    __shared__ float Bs[32][32];
    int tid = threadIdx.x;
    int tx = tid & 15;
    int ty = tid >> 4;
    int row0 = blockIdx.y * 64;
    int n0 = blockIdx.x * 32;
    float acc[4][2] = {{0.f, 0.f}, {0.f, 0.f}, {0.f, 0.f}, {0.f, 0.f}};
    int nt = Kk >> 5;
    for (int kt = 0; kt < nt; kt++) {
#pragma unroll
        for (int t = 0; t < 2; t++) {
            int f = tid + t * 256;
            int ar = f >> 3, ac = (f & 7) * 4;
            const float4 v = *reinterpret_cast<const float4*>(
                A + (size_t)(row0 + ar) * Kk + kt * 32 + ac);
            *reinterpret_cast<float4*>(&As[ar][ac]) = v;
        }
        {
            int br = tid >> 3, bc = (tid & 7) * 4;
            const float4 v = *reinterpret_cast<const float4*>(
                B + (size_t)(kt * 32 + br) * Nn + n0 + bc);
            *reinterpret_cast<float4*>(&Bs[br][bc]) = v;
        }
        __syncthreads();
#pragma unroll
        for (int k4 = 0; k4 < 8; k4++) {
            float4 a0 = *reinterpret_cast<float4*>(&As[ty * 4 + 0][k4 * 4]);
            float4 a1 = *reinterpret_cast<float4*>(&As[ty * 4 + 1][k4 * 4]);
            float4 a2 = *reinterpret_cast<float4*>(&As[ty * 4 + 2][k4 * 4]);
            float4 a3 = *reinterpret_cast<float4*>(&As[ty * 4 + 3][k4 * 4]);
            float2 b0 = *reinterpret_cast<float2*>(&Bs[k4 * 4 + 0][tx * 2]);
            float2 b1 = *reinterpret_cast<float2*>(&Bs[k4 * 4 + 1][tx * 2]);
            float2 b2 = *reinterpret_cast<float2*>(&Bs[k4 * 4 + 2][tx * 2]);
            float2 b3 = *reinterpret_cast<float2*>(&Bs[k4 * 4 + 3][tx * 2]);
            acc[0][0] = fmaf(a0.x, b0.x, acc[0][0]); acc[0][1] = fmaf(a0.x, b0.y, acc[0][1]);
            acc[1][0] = fmaf(a1.x, b0.x, acc[1][0]); acc[1][1] = fmaf(a1.x, b0.y, acc[1][1]);
            acc[2][0] = fmaf(a2.x, b0.x, acc[2][0]); acc[2][1] = fmaf(a2.x, b0.y, acc[2][1]);
            acc[3][0] = fmaf(a3.x, b0.x, acc[3][0]); acc[3][1] = fmaf(a3.x, b0.y, acc[3][1]);
            acc[0][0] = fmaf(a0.y, b1.x, acc[0][0]); acc[0][1] = fmaf(a0.y, b1.y, acc[0][1]);
            acc[1][0] = fmaf(a1.y, b1.x, acc[1][0]); acc[1][1] = fmaf(a1.y, b1.y, acc[1][1]);
            acc[2][0] = fmaf(a2.y, b1.x, acc[2][0]); acc[2][1] = fmaf(a2.y, b1.y, acc[2][1]);
            acc[3][0] = fmaf(a3.y, b1.x, acc[3][0]); acc[3][1] = fmaf(a3.y, b1.y, acc[3][1]);
            acc[0][0] = fmaf(a0.z, b2.x, acc[0][0]); acc[0][1] = fmaf(a0.z, b2.y, acc[0][1]);
            acc[1][0] = fmaf(a1.z, b2.x, acc[1][0]); acc[1][1] = fmaf(a1.z, b2.y, acc[1][1]);
            acc[2][0] = fmaf(a2.z, b2.x, acc[2][0]); acc[2][1] = fmaf(a2.z, b2.y, acc[2][1]);
            acc[3][0] = fmaf(a3.z, b2.x, acc[3][0]); acc[3][1] = fmaf(a3.z, b2.y, acc[3][1]);
            acc[0][0] = fmaf(a0.w, b3.x, acc[0][0]); acc[0][1] = fmaf(a0.w, b3.y, acc[0][1]);
            acc[1][0] = fmaf(a1.w, b3.x, acc[1][0]); acc[1][1] = fmaf(a1.w, b3.y, acc[1][1]);
            acc[2][0] = fmaf(a2.w, b3.x, acc[2][0]); acc[2][1] = fmaf(a2.w, b3.y, acc[2][1]);
            acc[3][0] = fmaf(a3.w, b3.x, acc[3][0]); acc[3][1] = fmaf(a3.w, b3.y, acc[3][1]);
        }
        __syncthreads();
    }
    int cc = n0 + tx * 2;
    float bx_ = 0.f, by_ = 0.f;
    if (HASB) { bx_ = bias[cc]; by_ = bias[cc + 1]; }
#pragma unroll
    for (int i = 0; i < 4; i++) {
        int rr = row0 + ty * 4 + i;
        float v0 = acc[i][0], v1 = acc[i][1];
        if (HASB) { v0 += bx_; v1 += by_; }
        if (ACT == 1) { v0 = geluf(v0); v1 = geluf(v1); }
        if (HASR) {
            const float2 r2 = *reinterpret_cast<const float2*>(res + (size_t)rr * Nn + cc);
            v0 += r2.x; v1 += r2.y;
        }
        float2 o; o.x = v0; o.y = v1;
        *reinterpret_cast<float2*>(C + (size_t)rr * Nn + cc) = o;
    }
}

// ---------------- depthwise 3x3 conv + bias + silu ----------------
__global__ void conv_silu_kernel(const float* __restrict__ xz, const float* __restrict__ cw,
                                 const float* __restrict__ cb, float* __restrict__ out) {
    int idx = blockIdx.x * 256 + threadIdx.x;
    if (idx >= cL * cDI) return;
    int d = idx % cDI;
    int l = idx / cDI;
    int h = l / cW, w = l % cW;
    float s = cb[d];
#pragma unroll
    for (int dh = 0; dh < 3; dh++) {
        int hh = h + dh - 1;
        if (hh < 0 || hh >= cH) continue;
#pragma unroll
        for (int dw = 0; dw < 3; dw++) {
            int w2 = w + dw - 1;
            if (w2 < 0 || w2 >= cW) continue;
            s = fmaf(xz[(size_t)(hh * cW + w2) * (2 * cDI) + d], cw[(dh * 3 + dw) * cDI + d], s);
        }
    }
    out[idx] = siluf(s);
}

// ---------------- x_proj + dt_proj; dt in [k][j][d], Bs/Cs in [k][j][n] ----------------
__global__ void proj_kernel(const float* __restrict__ xconv, const float* __restrict__ xpw,
                            const float* __restrict__ dtw, const float* __restrict__ dtb,
                            float* __restrict__ dtT, float* __restrict__ Bsout,
                            float* __restrict__ Csout) {
    __shared__ float XS[16 * 193];
    __shared__ float DTS[6 * 16];
    __shared__ float DTW[cDI * cDR];
    int k = blockIdx.y;
    int p0 = blockIdx.x * 16;
    int tid = threadIdx.x;
    for (int i = tid; i < cDI * cDR; i += 256) DTW[i] = dtw[k * cDI * cDR + i];
    for (int idx = tid; idx < 16 * cDI; idx += 256) {
        int p = idx / cDI, d = idx % cDI;
        int j = p0 + p;
        int jj = (k >= 2) ? (cL - 1 - j) : j;
        int rrow = (k & 1) ? ((jj % cH) * cW + (jj / cH)) : jj;
        XS[p * 193 + d] = xconv[(size_t)rrow * cDI + d];
    }
    __syncthreads();
    for (int o = tid; o < 38 * 16; o += 256) {
        int c = o >> 4, p = o & 15;
        const float* wr = xpw + (size_t)(k * 38 + c) * cDI;
        const float* xr = XS + p * 193;
        float s = 0.f;
#pragma unroll 4
        for (int d = 0; d < cDI; d++) s = fmaf(wr[d], xr[d], s);
        if (c < 6) DTS[c * 16 + p] = s;
        else if (c < 22) Bsout[(size_t)(k * cL + p0 + p) * cN + (c - 6)] = s;
        else Csout[(size_t)(k * cL + p0 + p) * cN + (c - 22)] = s;
    }
    __syncthreads();
    for (int o = tid; o < cDI * 16; o += 256) {
        int d = o % cDI, p = o / cDI;
        float s = dtb[k * cDI + d];
#pragma unroll
        for (int r = 0; r < cDR; r++) s = fmaf(DTW[d * cDR + r], DTS[r * 16 + p], s);
        float sp = (s > 20.f) ? s : log1pf(expf(s));
        dtT[(size_t)(k * cL + p0 + p) * cDI + d] = sp;
    }
}

// physical-row walker (wave-uniform)
__device__ __forceinline__ void walker_init(int k, int j0, int& r, int& dr) {
    if (k == 0) { r = j0; dr = 1; }
    else if (k == 1) { r = (j0 % cH) * cW + (j0 / cH); dr = cW; }
    else if (k == 2) { r = cL - 1 - j0; dr = -1; }
    else { int jp = cL - 1 - j0; r = (jp % cH) * cW + (jp / cH); dr = -cW; }
}
__device__ __forceinline__ void walker_step(int& r, int dr) {
    r += dr;
    if (r >= cL) r -= cL - 1;
    else if (r < 0) r += cL - 1;
}

// ---------------- scan pass 1 ----------------
__global__ __launch_bounds__(192) void scan1_kernel(
    const float* __restrict__ dtT, const float* __restrict__ Bs,
    const float* __restrict__ xconv, const float* __restrict__ Alogs,
    float* __restrict__ carryP, float* __restrict__ carryH) {
    int c = blockIdx.x % cNC;
    int k = blockIdx.x / cNC;
    int d = threadIdx.x;
    int kd = k * cDI + d;
    int j0 = c * cCH;
    __shared__ float BS[cCH * cN];
    for (int i = threadIdx.x; i < cCH * cN; i += 192)
        BS[i] = Bs[(size_t)(k * cL + j0) * cN + i];
    float An2[cN];
#pragma unroll
    for (int n = 0; n < cN; n++)
        An2[n] = -fast_exp2(Alogs[kd * cN + n] * LOG2E) * LOG2E;
    int r, dr;
    walker_init(k, j0, r, dr);
    __syncthreads();
    float h[cN];
#pragma unroll
    for (int n = 0; n < cN; n++) h[n] = 0.f;
    float S = 0.f;
    const float* dtp = dtT + (size_t)(k * cL + j0) * cDI + d;
    for (int i = 0; i < cCH; i++) {
        float dt = dtp[(size_t)i * cDI];
        float xv = xconv[r * cDI + d];
        walker_step(r, dr);
        float dtx = dt * xv;
        S += dt;
        const float4 b0 = *reinterpret_cast<const float4*>(&BS[i * cN + 0]);
        const float4 b1 = *reinterpret_cast<const float4*>(&BS[i * cN + 4]);
        const float4 b2 = *reinterpret_cast<const float4*>(&BS[i * cN + 8]);
        const float4 b3 = *reinterpret_cast<const float4*>(&BS[i * cN + 12]);
        float bb[cN] = {b0.x, b0.y, b0.z, b0.w, b1.x, b1.y, b1.z, b1.w,
                        b2.x, b2.y, b2.z, b2.w, b3.x, b3.y, b3.z, b3.w};
#pragma unroll
        for (int n = 0; n < cN; n++) {
            float a = fast_exp2(An2[n] * dt);
            h[n] = fmaf(a, h[n], bb[n] * dtx);
        }
    }
    size_t cb = (size_t)(kd * cNC + c) * cN;
#pragma unroll
    for (int n = 0; n < cN; n++) {
        carryH[cb + n] = h[n];
        carryP[cb + n] = fast_exp2(An2[n] * S);
    }
}

// ---------------- scan pass 2 ----------------
__global__ void scan2_kernel(const float* __restrict__ carryP, const float* __restrict__ carryH,
                             float* __restrict__ hin) {
    int gid = blockIdx.x * 256 + threadIdx.x;
    if (gid >= cK * cDI * cN) return;
    int kd = gid / cN, n = gid % cN;
    float h = 0.f;
    for (int c = 0; c < cNC; c++) {
        size_t idxc = (size_t)(kd * cNC + c) * cN + n;
        hin[idxc] = h;
        h = fmaf(carryP[idxc], h, carryH[idxc]);
    }
}

// ---------------- scan pass 3 ----------------
__global__ __launch_bounds__(192) void scan3_kernel(
    const float* __restrict__ dtT, const float* __restrict__ Bs,
    const float* __restrict__ Cs, const float* __restrict__ xconv,
    const float* __restrict__ Alogs, const float* __restrict__ Ds,
    const float* __restrict__ hin, float* __restrict__ ysS) {
    int c = blockIdx.x % cNC;
    int k = blockIdx.x / cNC;
    int d = threadIdx.x;
    int kd = k * cDI + d;
    int j0 = c * cCH;
    __shared__ float BS[cCH * cN];
    __shared__ float CS[cCH * cN];
    for (int i = threadIdx.x; i < cCH * cN; i += 192) {
        BS[i] = Bs[(size_t)(k * cL + j0) * cN + i];
        CS[i] = Cs[(size_t)(k * cL + j0) * cN + i];
    }
    float An2[cN];
#pragma unroll
    for (int n = 0; n < cN; n++)
        An2[n] = -fast_exp2(Alogs[kd * cN + n] * LOG2E) * LOG2E;
    float Dv = Ds[kd];
    int r, dr;
    walker_init(k, j0, r, dr);
    float h[cN];
    size_t cb = (size_t)(kd * cNC + c) * cN;
#pragma unroll
    for (int n = 0; n < cN; n++) h[n] = hin[cb + n];
    __syncthreads();
    const float* dtp = dtT + (size_t)(k * cL + j0) * cDI + d;
    float* yp = ysS + (size_t)(k * cL + j0) * cDI + d;
    for (int i = 0; i < cCH; i++) {
        float dt = dtp[(size_t)i * cDI];
        float xv = xconv[r * cDI + d];
        walker_step(r, dr);
        float dtx = dt * xv;
        const float4 b0 = *reinterpret_cast<const float4*>(&BS[i * cN + 0]);
        const float4 b1 = *reinterpret_cast<const float4*>(&BS[i * cN + 4]);
        const float4 b2 = *reinterpret_cast<const float4*>(&BS[i * cN + 8]);
        const float4 b3 = *reinterpret_cast<const float4*>(&BS[i * cN + 12]);
        float bb[cN] = {b0.x, b0.y, b0.z, b0.w, b1.x, b1.y, b1.z, b1.w,
                        b2.x, b2.y, b2.z, b2.w, b3.x, b3.y, b3.z, b3.w};
        const float4 c0 = *reinterpret_cast<const float4*>(&CS[i * cN + 0]);
        const float4 c1 = *reinterpret_cast<const float4*>(&CS[i * cN + 4]);
        const float4 c2 = *reinterpret_cast<const float4*>(&CS[i * cN + 8]);
        const float4 c3 = *reinterpret_cast<const float4*>(&CS[i * cN + 12]);
        float cc[cN] = {c0.x, c0.y, c0.z, c0.w, c1.x, c1.y, c1.z, c1.w,
                        c2.x, c2.y, c2.z, c2.w, c3.x, c3.y, c3.z, c3.w};
        float y0 = 0.f, y1 = 0.f, y2 = 0.f, y3 = 0.f;
#pragma unroll
        for (int n = 0; n < cN; n += 4) {
            float a0 = fast_exp2(An2[n + 0] * dt);
            float a1 = fast_exp2(An2[n + 1] * dt);
            float a2 = fast_exp2(An2[n + 2] * dt);
            float a3 = fast_exp2(An2[n + 3] * dt);
            h[n + 0] = fmaf(a0, h[n + 0], bb[n + 0] * dtx);
            h[n + 1] = fmaf(a1, h[n + 1], bb[n + 1] * dtx);
            h[n + 2] = fmaf(a2, h[n + 2], bb[n + 2] * dtx);
            h[n + 3] = fmaf(a3, h[n + 3], bb[n + 3] * dtx);
            y0 = fmaf(h[n + 0], cc[n + 0], y0);
            y1 = fmaf(h[n + 1], cc[n + 1], y1);
            y2 = fmaf(h[n + 2], cc[n + 2], y2);
            y3 = fmaf(h[n + 3], cc[n + 3], y3);
        }
        yp[(size_t)i * cDI] = (y0 + y1) + (y2 + y3) + Dv * xv;
    }
}

// ---------------- combine 4 directions + out-LN + silu(z) ----------------
__global__ void lnout_kernel(const float* __restrict__ ysS, const float* __restrict__ xz,
                             const float* __restrict__ g, const float* __restrict__ b,
                             float* __restrict__ ymul) {
    int wid = threadIdx.x >> 6, lane = threadIdx.x & 63;
    int l = blockIdx.x * 4 + wid;
    if (l >= cL) return;
    int h_ = l / cW, w_ = l % cW;
    int lc = w_ * cH + h_;
    float v[3];
    float s = 0.f, sq = 0.f;
#pragma unroll
    for (int j = 0; j < 3; j++) {
        int d = lane + j * 64;
        float t = ysS[(size_t)(0 * cL + l) * cDI + d] +
                  ysS[(size_t)(1 * cL + lc) * cDI + d] +
                  ysS[(size_t)(2 * cL + (cL - 1 - l)) * cDI + d] +
                  ysS[(size_t)(3 * cL + (cL - 1 - lc)) * cDI + d];
        v[j] = t;
        s += t;
        sq += t * t;
    }
#pragma unroll
    for (int off = 32; off; off >>= 1) {
        s += __shfl_xor(s, off, 64);
        sq += __shfl_xor(sq, off, 64);
    }
    float m = s * (1.f / cDI);
    float var = sq * (1.f / cDI) - m * m;
    float rstd = rsqrtf(var + 1e-5f);
#pragma unroll
    for (int j = 0; j < 3; j++) {
        int d = lane + j * 64;
        float z = xz[(size_t)l * (2 * cDI) + cDI + d];
        ymul[(size_t)l * cDI + d] = ((v[j] - m) * rstd * g[d] + b[d]) * siluf(z);
    }
}

extern "C" void kernel_launch(void* const* d_in, const int* in_sizes, int n_in,
                              void* d_out, int out_size, void* d_ws, size_t ws_size,
                              hipStream_t stream) {
    const float* x         = (const float*)d_in[0];
    const float* norm_g    = (const float*)d_in[1];
    const float* norm_b    = (const float*)d_in[2];
    const float* in_proj_w = (const float*)d_in[3];
    const float* conv_w    = (const float*)d_in[4];
    const float* conv_b    = (const float*)d_in[5];
    const float* x_proj_w  = (const float*)d_in[6];
    const float* dt_projs_w= (const float*)d_in[7];
    const float* dt_projs_b= (const float*)d_in[8];
    const float* A_logs    = (const float*)d_in[9];
    const float* Ds        = (const float*)d_in[10];
    const float* out_norm_g= (const float*)d_in[11];
    const float* out_norm_b= (const float*)d_in[12];
    const float* out_proj_w= (const float*)d_in[13];
    const float* norm2_g   = (const float*)d_in[14];
    const float* norm2_b   = (const float*)d_in[15];
    const float* fc1_w     = (const float*)d_in[16];
    const float* fc1_b     = (const float*)d_in[17];
    const float* fc2_w     = (const float*)d_in[18];
    const float* fc2_b     = (const float*)d_in[19];

    float* ws = (float*)d_ws;
    float* xz     = ws;                    // 1204224
    float* xconv  = ws + 1204224;          // 602112 (ymul aliases after scan3)
    float* dtT    = ws + 1806336;          // 2408448  [k][j][d]
    float* Bs     = ws + 4214784;          // 200704   [k][j][n]
    float* Cs     = ws + 4415488;          // 200704   [k][j][n]
    float* hin    = ws + 4616192;          // 1204224
    float* cP     = ws + 5820416;          // 1204224
    float* cHh    = ws + 7024640;          // 1204224
    float* ysS    = ws + 8228864;          // 2408448  [k][j][d]
    float* x1     = ws + 10637312;         // 301056
    float* ymul   = xconv;                 // reuse xconv (dead after scan3)
    float* hm     = xz;                    // reuse xz after lnout
    float* out    = (float*)d_out;

    // 1. LN1 + in_proj (L,96)@(96,384)
    gemm_ln_tile<0, false><<<dim3(384 / 32, cL / 64), 256, 0, stream>>>(
        x, norm_g, norm_b, in_proj_w, nullptr, xz, cL, 2 * cDI);
    // 2. depthwise conv + silu
    conv_silu_kernel<<<(cL * cDI) / 256, 256, 0, stream>>>(xz, conv_w, conv_b, xconv);
    // 3. x_proj + dt_proj (scan-order outputs)
    proj_kernel<<<dim3(cL / 16, cK), 256, 0, stream>>>(xconv, x_proj_w, dt_projs_w,
                                                       dt_projs_b, dtT, Bs, Cs);
    // 4-6. chunked scan
    scan1_kernel<<<cK * cNC, 192, 0, stream>>>(dtT, Bs, xconv, A_logs, cP, cHh);
    scan2_kernel<<<(cK * cDI * cN + 255) / 256, 256, 0, stream>>>(cP, cHh, hin);
    scan3_kernel<<<cK * cNC, 192, 0, stream>>>(dtT, Bs, Cs, xconv, A_logs, Ds, hin, ysS);
    // 7. combine + out-LN + silu(z)
    lnout_kernel<<<cL / 4, 256, 0, stream>>>(ysS, xz, out_norm_g, out_norm_b, ymul);
    // 8. out_proj + residual(x) (L,192)@(192,96)
    gemm_tile_kernel<0, false, true><<<dim3(96 / 32, cL / 64), 256, 0, stream>>>(
        ymul, out_proj_w, nullptr, x, x1, cL, cC, cDI);
    // 9. LN2 + fc1 + bias + gelu
    gemm_ln_tile<1, true><<<dim3(384 / 32, cL / 64), 256, 0, stream>>>(
        x1, norm2_g, norm2_b, fc1_w, fc1_b, hm, cL, cMH);
    // 10. fc2 + bias + residual(x1)
    gemm_tile_kernel<0, true, true><<<dim3(96 / 32, cL / 64), 256, 0, stream>>>(
        hm, fc2_w, fc2_b, x1, out, cL, cC, cMH);
}